// Round 16
// baseline (131.989 us; speedup 1.0000x reference)
//
#include <hip/hip_runtime.h>

typedef unsigned short ushort_t;
typedef __attribute__((ext_vector_type(8))) __bf16 bf16x8;
typedef __attribute__((ext_vector_type(4))) float f32x4;

#define GLD(src, lds) __builtin_amdgcn_global_load_lds( \
    (const __attribute__((address_space(1))) void*)(src), \
    (__attribute__((address_space(3))) void*)(lds), 16, 0, 0)

#if __has_builtin(__builtin_amdgcn_exp2f)
#define EXP2(x) __builtin_amdgcn_exp2f(x)
#else
#define EXP2(x) __expf((x) * 0.69314718f)
#endif
#define QK_SCALE 0.18033688f   /* 0.125 * log2(e) */

static __device__ __forceinline__ f32x4 mfma16(bf16x8 a, bf16x8 b, f32x4 c){
  return __builtin_amdgcn_mfma_f32_16x16x32_bf16(a, b, c, 0, 0, 0);
}
static __device__ __forceinline__ ushort_t f2bf(float f){
  unsigned u = __float_as_uint(f);
  return (ushort_t)((u + 0x7FFFu + ((u >> 16) & 1u)) >> 16);
}

// ---- swizzled staging / fragment reads, [R][64] bf16 tiles (flash/attmean) ----
template<int ROWS>
static __device__ __forceinline__ void stage64(const ushort_t* __restrict__ g, size_t rstride,
                                               ushort_t* lds, int tid){
#pragma unroll
  for (int r = 0; r < ROWS/32; ++r){
    int li = r*256 + tid;
    int row = li >> 3, ch = li & 7;
    GLD(g + (size_t)row*rstride + ((ch ^ (row & 7)) << 3),
        (char*)lds + (r*256 + (tid >> 6)*64)*16);
  }
}
static __device__ __forceinline__ bf16x8 frag64(const ushort_t* lds, int row, int ch){
  return *(const bf16x8*)((const char*)lds + row*128 + ((ch ^ (row & 7)) << 4));
}

// ---- [128][32] bf16 GEMM tiles (64B rows, 4 chunks of 16B), chunk ^= (row>>1)&3 ----
static __device__ __forceinline__ void stage32(const ushort_t* __restrict__ g, size_t rstride,
                                               ushort_t* lds, int tid){
#pragma unroll
  for (int r = 0; r < 2; ++r){
    int li = r*256 + tid;
    int row = li >> 2, ch = li & 3;
    GLD(g + (size_t)row*rstride + ((ch ^ ((row >> 1) & 3)) << 3),
        (char*)lds + (r*256 + (tid >> 6)*64)*16);
  }
}
static __device__ __forceinline__ bf16x8 frag32(const ushort_t* lds, int row, int ch){
  return *(const bf16x8*)((const char*)lds + row*64 + ((ch ^ ((row >> 1) & 3)) << 4));
}

// ---- fp32 operand reg-staging (R15-verified on A; same involution as stage32) ----
// Thread li loads the fp32 source chunk stage32 would place at its linear LDS slot;
// after RNE cvt the bf16 tile is byte-identical to a stage32-staged tile ->
// frag32 reads it conflict-free.
static __device__ __forceinline__ void load_f32(const float* __restrict__ g,
                                                float4 (&d)[2][2], int tid){
#pragma unroll
  for (int r = 0; r < 2; ++r){
    int li = r*256 + tid;
    int row = li >> 2;
    int lc = (li & 3) ^ ((row >> 1) & 3);
    const float* s = g + (size_t)row*1024 + lc*8;
    d[r][0] = ((const float4*)s)[0];
    d[r][1] = ((const float4*)s)[1];
  }
}
static __device__ __forceinline__ void commit_f32(const float4 (&d)[2][2],
                                                  ushort_t* lds, int tid){
#pragma unroll
  for (int r = 0; r < 2; ++r){
    int li = r*256 + tid;
    bf16x8 o;
    o[0] = (__bf16)d[r][0].x; o[1] = (__bf16)d[r][0].y;
    o[2] = (__bf16)d[r][0].z; o[3] = (__bf16)d[r][0].w;
    o[4] = (__bf16)d[r][1].x; o[5] = (__bf16)d[r][1].y;
    o[6] = (__bf16)d[r][1].z; o[7] = (__bf16)d[r][1].w;
    *(bf16x8*)((char*)lds + li*16) = o;
  }
}

// ---------------- Wo-only cast fp32 -> bf16 (2 MB traffic, ~1 us) ----------------
__global__ __launch_bounds__(256) void cast_w(const float* __restrict__ wo,
                                              ushort_t* __restrict__ wob)
{
  int i = blockIdx.x*256 + threadIdx.x;   // 262144 float4 groups
  float4 x = ((const float4*)wo)[i];
  ushort4 o;
  o.x = f2bf(x.x); o.y = f2bf(x.y); o.z = f2bf(x.z); o.w = f2bf(x.w);
  ((ushort4*)wob)[i] = o;
}

// ---------------- QKV GEMM: C = A_f32[M,K] * B_f32[N,K]^T + bias ----------------
// 128x128 tile, BK=32, 2-phase dbuf, one barrier/K-step, 32KB LDS. BOTH operands
// fp32 reg-staged with in-GEMM RNE cast (no cast pass at all for Q/K/V weights).
// Loads for kt+1 issue at loop top; cvt+ds_write after MFMA (T14 split).
// XCD stripe: xcd=bx&7 owns a 512-row A-stripe (L2-resident).
// mode 0: bf16 -> [b,h,t,d]; mode 1: bf16 -> [b,h,d,t].
static __device__ __forceinline__ void gemm_f32_body(const float* __restrict__ A,
    const float* __restrict__ B, const float* __restrict__ bias,
    void* __restrict__ Cout, int bx, int mode, char* smem)
{
  constexpr int K = 1024;
  ushort_t* As0 = (ushort_t*)smem;                    // 8KB bf16
  ushort_t* As1 = (ushort_t*)(smem + 8192);           // 8KB
  ushort_t* Bs0 = (ushort_t*)(smem + 16384);          // 8KB
  ushort_t* Bs1 = (ushort_t*)(smem + 24576);          // 8KB -> 32KB total
  const int tid = threadIdx.x, lane = tid & 63, wv = tid >> 6;
  const int fr = lane & 15, fq = lane >> 4;
  const int wr = wv >> 1, wc = wv & 1;
  const int brow0 = ((bx & 7) * 4 + ((bx >> 3) & 3)) * 128;
  const int bcol0 = (bx >> 5) * 128;

  const f32x4 zero = {0.f, 0.f, 0.f, 0.f};
  f32x4 acc[4][4];
#pragma unroll
  for (int m = 0; m < 4; ++m)
#pragma unroll
    for (int n = 0; n < 4; ++n) acc[m][n] = zero;

  float4 pfA[2][2], pfB[2][2];
  load_f32(A + (size_t)brow0*K, pfA, tid);
  load_f32(B + (size_t)bcol0*K, pfB, tid);
  commit_f32(pfA, As0, tid);
  commit_f32(pfB, Bs0, tid);
  __syncthreads();

  for (int kt = 0; kt < K/32; ++kt){
    const int cur = kt & 1;
    ushort_t* Ac = cur ? As1 : As0;
    ushort_t* Bc = cur ? Bs1 : Bs0;
    ushort_t* An = cur ? As0 : As1;
    ushort_t* Bn = cur ? Bs0 : Bs1;
    if (kt < K/32 - 1){
      load_f32(A + (size_t)brow0*K + (kt+1)*32, pfA, tid);   // issue early
      load_f32(B + (size_t)bcol0*K + (kt+1)*32, pfB, tid);
    }
    bf16x8 af[4], bfg[4];
#pragma unroll
    for (int m = 0; m < 4; ++m) af[m]  = frag32(Ac, wr*64 + m*16 + fr, fq);
#pragma unroll
    for (int n = 0; n < 4; ++n) bfg[n] = frag32(Bc, wc*64 + n*16 + fr, fq);
    __builtin_amdgcn_s_setprio(1);
#pragma unroll
    for (int m = 0; m < 4; ++m)
#pragma unroll
      for (int n = 0; n < 4; ++n)
        acc[m][n] = mfma16(af[m], bfg[n], acc[m][n]);
    __builtin_amdgcn_s_setprio(0);
    if (kt < K/32 - 1){
      commit_f32(pfA, An, tid);   // cvt + ds_write after MFMA (loads have landed)
      commit_f32(pfB, Bn, tid);
    }
    __syncthreads();
  }

#pragma unroll
  for (int n = 0; n < 4; ++n){
    const int colg = bcol0 + wc*64 + n*16 + fr;
    const float bv = bias[colg];
#pragma unroll
    for (int m = 0; m < 4; ++m){
      const int rowg0 = brow0 + wr*64 + m*16 + fq*4;
      if (mode == 1){
        // V^T [b,h,d,t]: 4 consecutive t -> one 8B store
        int b = rowg0 >> 10, t = rowg0 & 1023, h = colg >> 6, d = colg & 63;
        ushort4 o;
        o.x = f2bf(acc[m][n][0] + bv); o.y = f2bf(acc[m][n][1] + bv);
        o.z = f2bf(acc[m][n][2] + bv); o.w = f2bf(acc[m][n][3] + bv);
        *(ushort4*)((ushort_t*)Cout + (((size_t)(b*16 + h))*64 + d)*1024 + t) = o;
      } else {
#pragma unroll
        for (int r = 0; r < 4; ++r){
          const int rowg = rowg0 + r;
          float val = acc[m][n][r] + bv;
          int b = rowg >> 10, t = rowg & 1023, h = colg >> 6, d = colg & 63;
          ((ushort_t*)Cout)[(((size_t)(b*16 + h))*1024 + t)*64 + d] = f2bf(val);
        }
      }
    }
  }
}

// batched Q/K/V projections straight from fp32 inputs AND fp32 weights
__global__ __launch_bounds__(256) void gemm_qkv(const float* q, const float* k,
    const float* v, const float* wq, const float* wk, const float* wv,
    const float* bq, const float* bk, const float* bv,
    ushort_t* Qm, ushort_t* Km, ushort_t* Vtm)
{
  __shared__ char smem[32768];
  int id = blockIdx.x >> 8, bx = blockIdx.x & 255;
  const float* A = id==0 ? q : id==1 ? k : v;
  const float* B = id==0 ? wq : id==1 ? wk : wv;
  const float* bias = id==0 ? bq : id==1 ? bk : bv;
  void* C = id==0 ? (void*)Qm : id==1 ? (void*)Km : (void*)Vtm;
  gemm_f32_body(A, B, bias, C, bx, id==2 ? 1 : 0, smem);
}

// ---------------- pipelined bf16 GEMM body (R10-verified, used by fused tail) ----------
// 128x128 tile, BK=32, THREE LDS buffers, 2-deep prefetch, counted vmcnt + raw barrier.
static __device__ __forceinline__ void gemm_body(const ushort_t* __restrict__ A,
    const ushort_t* __restrict__ B, const float* __restrict__ bias,
    void* __restrict__ Cout, int bx, char* smem)
{
  constexpr int K = 1024;
  const int tid = threadIdx.x, lane = tid & 63, wv = tid >> 6;
  const int fr = lane & 15, fq = lane >> 4;
  const int wr = wv >> 1, wc = wv & 1;
  const int brow0 = ((bx & 7) * 4 + ((bx >> 3) & 3)) * 128;
  const int bcol0 = (bx >> 5) * 128;

  const f32x4 zero = {0.f, 0.f, 0.f, 0.f};
  f32x4 acc[4][4];
#pragma unroll
  for (int m = 0; m < 4; ++m)
#pragma unroll
    for (int n = 0; n < 4; ++n) acc[m][n] = zero;

  const ushort_t* Abase = A + (size_t)brow0*K;
  const ushort_t* Bbase = B + (size_t)bcol0*K;

  stage32(Abase,      K, (ushort_t*)(smem),             tid);
  stage32(Bbase,      K, (ushort_t*)(smem + 24576),     tid);
  stage32(Abase + 32, K, (ushort_t*)(smem + 8192),      tid);
  stage32(Bbase + 32, K, (ushort_t*)(smem + 24576 + 8192), tid);
  asm volatile("s_waitcnt vmcnt(4)" ::: "memory");
  __builtin_amdgcn_s_barrier();

  int rd = 0, wrb = 2;
  for (int kt = 0; kt < 32; ++kt){
    if (kt < 30){
      stage32(Abase + (kt+2)*32, K, (ushort_t*)(smem + wrb*8192),         tid);
      stage32(Bbase + (kt+2)*32, K, (ushort_t*)(smem + 24576 + wrb*8192), tid);
    }
    const ushort_t* Ac = (const ushort_t*)(smem + rd*8192);
    const ushort_t* Bc = (const ushort_t*)(smem + 24576 + rd*8192);
    bf16x8 af[4], bfg[4];
#pragma unroll
    for (int m = 0; m < 4; ++m) af[m]  = frag32(Ac, wr*64 + m*16 + fr, fq);
#pragma unroll
    for (int n = 0; n < 4; ++n) bfg[n] = frag32(Bc, wc*64 + n*16 + fr, fq);
    __builtin_amdgcn_s_setprio(1);
#pragma unroll
    for (int m = 0; m < 4; ++m)
#pragma unroll
      for (int n = 0; n < 4; ++n)
        acc[m][n] = mfma16(af[m], bfg[n], acc[m][n]);
    __builtin_amdgcn_s_setprio(0);
    __builtin_amdgcn_sched_barrier(0);
    if (kt < 30) asm volatile("s_waitcnt vmcnt(4)" ::: "memory");
    else         asm volatile("s_waitcnt vmcnt(0)" ::: "memory");
    __builtin_amdgcn_s_barrier();
    rd  = (rd  == 2) ? 0 : rd  + 1;
    wrb = (wrb == 2) ? 0 : wrb + 1;
  }

#pragma unroll
  for (int n = 0; n < 4; ++n){
    const int colg = bcol0 + wc*64 + n*16 + fr;
    const float bv = bias[colg];
#pragma unroll
    for (int m = 0; m < 4; ++m){
      const int rowg0 = brow0 + wr*64 + m*16 + fq*4;
#pragma unroll
      for (int r = 0; r < 4; ++r){
        const int rowg = rowg0 + r;
        ((float*)Cout)[(size_t)rowg*1024 + colg] = acc[m][n][r] + bv;
      }
    }
  }
}

// ---------------- attention mean over heads (recompute, m=0, Lrow only) ----------------
static __device__ __forceinline__ void attmean_body(const ushort_t* __restrict__ Q,
    const ushort_t* __restrict__ Kmat, const float* __restrict__ Lrow,
    float* __restrict__ attOut, int nb, char* smem)
{
  ushort_t* Qs0 = (ushort_t*)smem;
  ushort_t* Qs1 = (ushort_t*)(smem + 8192);
  ushort_t* Ks0 = (ushort_t*)(smem + 16384);
  ushort_t* Ks1 = (ushort_t*)(smem + 32768);
  const int tid = threadIdx.x, lane = tid & 63, wv = tid >> 6;
  const int fr = lane & 15, fq = lane >> 4;
  const int c_ = nb & 7, k_ = nb >> 3;
  const int b = c_ >> 1;
  const int rem = (c_ & 1)*64 + k_;
  const int t0 = (rem >> 3) * 64, s0 = (rem & 7) * 128;

  const f32x4 zero = {0.f, 0.f, 0.f, 0.f};
  f32x4 acc[2][4];
#pragma unroll
  for (int c = 0; c < 2; ++c)
#pragma unroll
    for (int n = 0; n < 4; ++n) acc[c][n] = zero;

  stage64<64>(Q + ((size_t)(b*16)*1024 + t0)*64, 64, Qs0, tid);
  stage64<128>(Kmat + ((size_t)(b*16)*1024 + s0)*64, 64, Ks0, tid);
  __syncthreads();

  for (int h = 0; h < 16; ++h){
    const int cur = h & 1;
    ushort_t* Qc = cur ? Qs1 : Qs0;
    ushort_t* Kc = cur ? Ks1 : Ks0;
    ushort_t* Qn = cur ? Qs0 : Qs1;
    ushort_t* Kn = cur ? Ks0 : Ks1;
    if (h < 15){
      stage64<64>(Q + ((size_t)(b*16 + h+1)*1024 + t0)*64, 64, Qn, tid);
      stage64<128>(Kmat + ((size_t)(b*16 + h+1)*1024 + s0)*64, 64, Kn, tid);
    }
    const int bh = b*16 + h;
    bf16x8 qf0 = frag64(Qc, wv*16 + fr, fq);
    bf16x8 qf1 = frag64(Qc, wv*16 + fr, 4 + fq);
    const float il = 1.f / Lrow[bh*1024 + t0 + wv*16 + fr];
#pragma unroll
    for (int c = 0; c < 2; ++c){
      f32x4 sfr[4];
      __builtin_amdgcn_s_setprio(1);
#pragma unroll
      for (int n = 0; n < 4; ++n){
        f32x4 s0v = mfma16(frag64(Kc, c*64 + n*16 + fr, fq), qf0, zero);
        sfr[n] = mfma16(frag64(Kc, c*64 + n*16 + fr, 4 + fq), qf1, s0v);
      }
      __builtin_amdgcn_s_setprio(0);
#pragma unroll
      for (int n = 0; n < 4; ++n)
#pragma unroll
        for (int r = 0; r < 4; ++r)
          acc[c][n][r] += EXP2(sfr[n][r] * QK_SCALE) * il;
    }
    __syncthreads();
  }

  const float s16 = 1.f/16.f;
#pragma unroll
  for (int c = 0; c < 2; ++c)
#pragma unroll
    for (int n = 0; n < 4; ++n){
      f32x4 v = acc[c][n];
      v[0] *= s16; v[1] *= s16; v[2] *= s16; v[3] *= s16;
      size_t idx = ((size_t)b << 20) + (size_t)(t0 + wv*16 + fr)*1024 + s0 + c*64 + n*16 + fq*4;
      *(f32x4*)(attOut + idx) = v;
    }
}

// ---------------- fused tail: gemm_o (blocks 0..255) + attmean (256..767) ----------------
__global__ __launch_bounds__(256) void fused_tail(const ushort_t* __restrict__ Yws,
    const ushort_t* __restrict__ Wob, const float* __restrict__ bo, float* __restrict__ y_out,
    const ushort_t* __restrict__ Qm, const ushort_t* __restrict__ Km,
    const float* __restrict__ Lrow, float* __restrict__ att_out)
{
  __shared__ char smem[49152];
  const int bx = blockIdx.x;
  if (bx < 256) gemm_body(Yws, Wob, bo, y_out, bx, smem);
  else          attmean_body(Qm, Km, Lrow, att_out, bx - 256, smem);
}

// ---------------- flash attention (R6-verified): QBLK=128, no online softmax ----------------
__global__ __launch_bounds__(256, 2) void flash_kernel(const ushort_t* __restrict__ Q,
                                                       const ushort_t* __restrict__ Kmat,
                                                       const ushort_t* __restrict__ Vt,
                                                       ushort_t* __restrict__ Yws,
                                                       float* __restrict__ Lrow)
{
  __shared__ ushort_t Ks[2][64][64];
  __shared__ ushort_t Vts[2][64][64];
  __shared__ ushort_t Ps[4][32][64];   // per-wave P tile; doubles as Q staging (128 rows)
  const int tid = threadIdx.x, lane = tid & 63, wv = tid >> 6;
  const int fr = lane & 15, fq = lane >> 4;
  const int nb = blockIdx.x;
  const int bh = (nb & 7)*8 + (nb >> 6);
  const int t0 = ((nb >> 3) & 7) * 128;

  stage64<128>(Q + ((size_t)bh*1024 + t0)*64, 64, &Ps[0][0][0], tid);
  stage64<64>(Kmat + (size_t)bh*1024*64, 64, &Ks[0][0][0], tid);
  stage64<64>(Vt + (size_t)bh*64*1024, 1024, &Vts[0][0][0], tid);
  __syncthreads();
  bf16x8 aQ[2][2];
#pragma unroll
  for (int mt = 0; mt < 2; ++mt)
#pragma unroll
    for (int h = 0; h < 2; ++h)
      aQ[mt][h] = frag64(&Ps[0][0][0], wv*32 + mt*16 + fr, h*4 + fq);
  __syncthreads();

  bf16x8 ones;
#pragma unroll
  for (int i = 0; i < 8; ++i) ones[i] = (__bf16)1.0f;

  const f32x4 zero = {0.f, 0.f, 0.f, 0.f};
  f32x4 o_acc[2][4], l_acc[2];
#pragma unroll
  for (int mt = 0; mt < 2; ++mt){
    l_acc[mt] = zero;
#pragma unroll
    for (int n = 0; n < 4; ++n) o_acc[mt][n] = zero;
  }
  char* myP = (char*)&Ps[wv][0][0];

  for (int sc = 0; sc < 16; ++sc){
    const int cur = sc & 1;
    if (sc < 15){
      stage64<64>(Kmat + ((size_t)bh*1024 + (sc+1)*64)*64, 64, &Ks[cur^1][0][0], tid);
      stage64<64>(Vt + (size_t)bh*64*1024 + (sc+1)*64, 1024, &Vts[cur^1][0][0], tid);
    }
    bf16x8 kf[4][2];
#pragma unroll
    for (int n = 0; n < 4; ++n){
      kf[n][0] = frag64(&Ks[cur][0][0], n*16 + fr, fq);
      kf[n][1] = frag64(&Ks[cur][0][0], n*16 + fr, 4 + fq);
    }
    f32x4 sfr[2][4];
    __builtin_amdgcn_s_setprio(1);
#pragma unroll
    for (int mt = 0; mt < 2; ++mt)
#pragma unroll
      for (int n = 0; n < 4; ++n){
        f32x4 s0 = mfma16(kf[n][0], aQ[mt][0], zero);
        sfr[mt][n] = mfma16(kf[n][1], aQ[mt][1], s0);
      }
    __builtin_amdgcn_s_setprio(0);
#pragma unroll
    for (int mt = 0; mt < 2; ++mt){
#pragma unroll
      for (int n = 0; n < 4; ++n){
        float p0 = EXP2(sfr[mt][n][0] * QK_SCALE);
        float p1 = EXP2(sfr[mt][n][1] * QK_SCALE);
        float p2 = EXP2(sfr[mt][n][2] * QK_SCALE);
        float p3 = EXP2(sfr[mt][n][3] * QK_SCALE);
        uint2 w;
        w.x = (unsigned)f2bf(p0) | ((unsigned)f2bf(p1) << 16);
        w.y = (unsigned)f2bf(p2) | ((unsigned)f2bf(p3) << 16);
        *(uint2*)(myP + mt*2048 + fr*128 + (((n*4 + fq) ^ (fr & 14)) << 3)) = w;
      }
    }
    // FENCE: P ds_writes must complete & stay ordered before P ds_reads (same wave)
    asm volatile("s_waitcnt lgkmcnt(0)" ::: "memory");
    __builtin_amdgcn_sched_barrier(0);
    __builtin_amdgcn_s_setprio(1);
#pragma unroll
    for (int ks = 0; ks < 2; ++ks){
      bf16x8 pa[2];
#pragma unroll
      for (int mt = 0; mt < 2; ++mt){
        uint4 u = *(const uint4*)(myP + mt*2048 + fr*128 + (((ks*8 + fq*2) ^ (fr & 14)) << 3));
        pa[mt] = __builtin_bit_cast(bf16x8, u);
      }
#pragma unroll
      for (int n = 0; n < 4; ++n){
        bf16x8 vf = frag64(&Vts[cur][0][0], n*16 + fr, ks*4 + fq);
#pragma unroll
        for (int mt = 0; mt < 2; ++mt)
          o_acc[mt][n] = mfma16(pa[mt], vf, o_acc[mt][n]);
      }
#pragma unroll
      for (int mt = 0; mt < 2; ++mt)
        l_acc[mt] = mfma16(pa[mt], ones, l_acc[mt]);
    }
    __builtin_amdgcn_s_setprio(0);
    __syncthreads();
  }

  const int b = bh >> 4, h = bh & 15;
#pragma unroll
  for (int mt = 0; mt < 2; ++mt){
    float inv[4];
#pragma unroll
    for (int r = 0; r < 4; ++r) inv[r] = 1.f / l_acc[mt][r];
#pragma unroll
    for (int n = 0; n < 4; ++n)
#pragma unroll
      for (int r = 0; r < 4; ++r){
        size_t row = (size_t)b*1024 + t0 + wv*32 + mt*16 + fq*4 + r;
        Yws[row*1024 + h*64 + n*16 + fr] = f2bf(o_acc[mt][n][r] * inv[r]);
      }
  }
  if (fr == 0){
#pragma unroll
    for (int mt = 0; mt < 2; ++mt)
#pragma unroll
      for (int r = 0; r < 4; ++r)
        Lrow[bh*1024 + t0 + wv*32 + mt*16 + fq*4 + r] = l_acc[mt][r];
  }
}

// ---------------- launch ----------------
extern "C" void kernel_launch(void* const* d_in, const int* in_sizes, int n_in,
                              void* d_out, int out_size, void* d_ws, size_t ws_size,
                              hipStream_t stream)
{
  const float* q_in = (const float*)d_in[0];
  const float* k_in = (const float*)d_in[1];
  const float* v_in = (const float*)d_in[2];
  const float* Wq   = (const float*)d_in[3];
  const float* bq   = (const float*)d_in[4];
  const float* Wk   = (const float*)d_in[5];
  const float* bk   = (const float*)d_in[6];
  const float* Wv   = (const float*)d_in[7];
  const float* bv   = (const float*)d_in[8];
  const float* Wo   = (const float*)d_in[9];
  const float* bo   = (const float*)d_in[10];

  float* y_out   = (float*)d_out;
  float* att_out = y_out + (size_t)4*1024*1024;

  char* ws = (char*)d_ws;
  const size_t MB = 1024*1024;
  ushort_t* wob  = (ushort_t*)(ws + 30*MB);
  ushort_t* Qm   = (ushort_t*)(ws + 32*MB);
  ushort_t* Km   = (ushort_t*)(ws + 40*MB);
  ushort_t* Vtm  = (ushort_t*)(ws + 48*MB);
  ushort_t* Yws  = (ushort_t*)(ws + 56*MB);
  float*    Lrow = (float*)(ws + 64*MB);

  cast_w<<<1024, 256, 0, stream>>>(Wo, wob);

  gemm_qkv<<<768, 256, 0, stream>>>(q_in, k_in, v_in, Wq, Wk, Wv,
                                    bq, bk, bv, Qm, Km, Vtm);

  flash_kernel<<<512, 256, 0, stream>>>(Qm, Km, Vtm, Yws, Lrow);

  fused_tail<<<768, 256, 0, stream>>>(Yws, wob, bo, y_out, Qm, Km, Lrow, att_out);
}

// Round 17
// 120.266 us; speedup vs baseline: 1.0975x; 1.0975x over previous
//
#include <hip/hip_runtime.h>

typedef unsigned short ushort_t;
typedef __attribute__((ext_vector_type(8))) __bf16 bf16x8;
typedef __attribute__((ext_vector_type(4))) float f32x4;

#define GLD(src, lds) __builtin_amdgcn_global_load_lds( \
    (const __attribute__((address_space(1))) void*)(src), \
    (__attribute__((address_space(3))) void*)(lds), 16, 0, 0)

#if __has_builtin(__builtin_amdgcn_exp2f)
#define EXP2(x) __builtin_amdgcn_exp2f(x)
#else
#define EXP2(x) __expf((x) * 0.69314718f)
#endif
#define QK_SCALE 0.18033688f   /* 0.125 * log2(e) */

static __device__ __forceinline__ f32x4 mfma16(bf16x8 a, bf16x8 b, f32x4 c){
  return __builtin_amdgcn_mfma_f32_16x16x32_bf16(a, b, c, 0, 0, 0);
}
static __device__ __forceinline__ ushort_t f2bf(float f){
  unsigned u = __float_as_uint(f);
  return (ushort_t)((u + 0x7FFFu + ((u >> 16) & 1u)) >> 16);
}

// ---- swizzled staging / fragment reads, [R][64] bf16 tiles (flash/attmean) ----
template<int ROWS>
static __device__ __forceinline__ void stage64(const ushort_t* __restrict__ g, size_t rstride,
                                               ushort_t* lds, int tid){
#pragma unroll
  for (int r = 0; r < ROWS/32; ++r){
    int li = r*256 + tid;
    int row = li >> 3, ch = li & 7;
    GLD(g + (size_t)row*rstride + ((ch ^ (row & 7)) << 3),
        (char*)lds + (r*256 + (tid >> 6)*64)*16);
  }
}
static __device__ __forceinline__ bf16x8 frag64(const ushort_t* lds, int row, int ch){
  return *(const bf16x8*)((const char*)lds + row*128 + ((ch ^ (row & 7)) << 4));
}

// ---- [128][32] bf16 GEMM tiles (64B rows, 4 chunks of 16B), chunk ^= (row>>1)&3 ----
static __device__ __forceinline__ void stage32(const ushort_t* __restrict__ g, size_t rstride,
                                               ushort_t* lds, int tid){
#pragma unroll
  for (int r = 0; r < 2; ++r){
    int li = r*256 + tid;
    int row = li >> 2, ch = li & 3;
    GLD(g + (size_t)row*rstride + ((ch ^ ((row >> 1) & 3)) << 3),
        (char*)lds + (r*256 + (tid >> 6)*64)*16);
  }
}
static __device__ __forceinline__ bf16x8 frag32(const ushort_t* lds, int row, int ch){
  return *(const bf16x8*)((const char*)lds + row*64 + ((ch ^ ((row >> 1) & 3)) << 4));
}

// ---- A reg-staging (R15-verified): fp32 global -> regs (issue-early) -> RNE cvt ->
// bf16 LDS in the stage32 layout (same XOR involution) -> frag32 reads conflict-free.
static __device__ __forceinline__ void loadA_f32(const float* __restrict__ g,
                                                 float4 (&d)[2][2], int tid){
#pragma unroll
  for (int r = 0; r < 2; ++r){
    int li = r*256 + tid;
    int row = li >> 2;
    int lc = (li & 3) ^ ((row >> 1) & 3);
    const float* s = g + (size_t)row*1024 + lc*8;
    d[r][0] = ((const float4*)s)[0];
    d[r][1] = ((const float4*)s)[1];
  }
}
static __device__ __forceinline__ void commitA(const float4 (&d)[2][2],
                                               ushort_t* lds, int tid){
#pragma unroll
  for (int r = 0; r < 2; ++r){
    int li = r*256 + tid;
    bf16x8 o;
    o[0] = (__bf16)d[r][0].x; o[1] = (__bf16)d[r][0].y;
    o[2] = (__bf16)d[r][0].z; o[3] = (__bf16)d[r][0].w;
    o[4] = (__bf16)d[r][1].x; o[5] = (__bf16)d[r][1].y;
    o[6] = (__bf16)d[r][1].z; o[7] = (__bf16)d[r][1].w;
    *(bf16x8*)((char*)lds + li*16) = o;
  }
}

// ---------------- QKV weight cast fp32 -> bf16 (Wq/Wk/Wv, 3072 blocks) ----------------
__global__ __launch_bounds__(256) void cast_w(const float* __restrict__ wq,
    const float* __restrict__ wk, const float* __restrict__ wv,
    char* __restrict__ ws)
{
  const size_t MB = 1024*1024;
  int i = blockIdx.x*256 + threadIdx.x;   // 786432 float4 groups
  int w = i >> 18, j = i & 262143;
  const float* src = w==0 ? wq : w==1 ? wk : wv;
  ushort_t* dst = (ushort_t*)(ws + (24 + 2*(size_t)w)*MB);
  float4 x = ((const float4*)src)[j];
  ushort4 o;
  o.x = f2bf(x.x); o.y = f2bf(x.y); o.z = f2bf(x.z); o.w = f2bf(x.w);
  ((ushort4*)dst)[j] = o;
}

// ---------------- QKV GEMM (R15-verified): C = A_f32[M,K] * B_bf16[N,K]^T + bias ----
// 128x128 tile, BK=32, 2-phase dbuf, one barrier/K-step, 32KB LDS. A fp32
// reg-staged with early cvt; B bf16 via global_load_lds. T14 split: loads for
// kt+1 issue at loop top, cvt+ds_write after MFMA. XCD stripe: xcd=bx&7 owns a
// 512-row A-stripe. mode 0: bf16 -> [b,h,t,d]; mode 1: bf16 -> [b,h,d,t].
static __device__ __forceinline__ void gemm_f32_body(const float* __restrict__ A,
    const ushort_t* __restrict__ B, const float* __restrict__ bias,
    void* __restrict__ Cout, int bx, int mode, char* smem)
{
  constexpr int K = 1024;
  ushort_t* As0 = (ushort_t*)smem;                    // 8KB bf16
  ushort_t* As1 = (ushort_t*)(smem + 8192);           // 8KB
  ushort_t* Bs0 = (ushort_t*)(smem + 16384);          // 8KB
  ushort_t* Bs1 = (ushort_t*)(smem + 24576);          // 8KB -> 32KB total
  const int tid = threadIdx.x, lane = tid & 63, wv = tid >> 6;
  const int fr = lane & 15, fq = lane >> 4;
  const int wr = wv >> 1, wc = wv & 1;
  const int brow0 = ((bx & 7) * 4 + ((bx >> 3) & 3)) * 128;
  const int bcol0 = (bx >> 5) * 128;

  const f32x4 zero = {0.f, 0.f, 0.f, 0.f};
  f32x4 acc[4][4];
#pragma unroll
  for (int m = 0; m < 4; ++m)
#pragma unroll
    for (int n = 0; n < 4; ++n) acc[m][n] = zero;

  float4 pfA[2][2];
  loadA_f32(A + (size_t)brow0*K, pfA, tid);
  commitA(pfA, As0, tid);
  stage32(B + (size_t)bcol0*K, K, Bs0, tid);
  __syncthreads();

  for (int kt = 0; kt < K/32; ++kt){
    const int cur = kt & 1;
    ushort_t* Ac = cur ? As1 : As0;
    ushort_t* Bc = cur ? Bs1 : Bs0;
    ushort_t* An = cur ? As0 : As1;
    ushort_t* Bn = cur ? Bs0 : Bs1;
    if (kt < K/32 - 1){
      loadA_f32(A + (size_t)brow0*K + (kt+1)*32, pfA, tid);   // issue early
      stage32(B + (size_t)bcol0*K + (kt+1)*32, K, Bn, tid);
    }
    bf16x8 af[4], bfg[4];
#pragma unroll
    for (int m = 0; m < 4; ++m) af[m]  = frag32(Ac, wr*64 + m*16 + fr, fq);
#pragma unroll
    for (int n = 0; n < 4; ++n) bfg[n] = frag32(Bc, wc*64 + n*16 + fr, fq);
    __builtin_amdgcn_s_setprio(1);
#pragma unroll
    for (int m = 0; m < 4; ++m)
#pragma unroll
      for (int n = 0; n < 4; ++n)
        acc[m][n] = mfma16(af[m], bfg[n], acc[m][n]);
    __builtin_amdgcn_s_setprio(0);
    if (kt < K/32 - 1)
      commitA(pfA, An, tid);    // cvt + ds_write after MFMA (loads have landed)
    __syncthreads();            // drains B GLDs + A ds_writes
  }

#pragma unroll
  for (int n = 0; n < 4; ++n){
    const int colg = bcol0 + wc*64 + n*16 + fr;
    const float bv = bias[colg];
#pragma unroll
    for (int m = 0; m < 4; ++m){
      const int rowg0 = brow0 + wr*64 + m*16 + fq*4;
      if (mode == 1){
        // V^T [b,h,d,t]: 4 consecutive t -> one 8B store
        int b = rowg0 >> 10, t = rowg0 & 1023, h = colg >> 6, d = colg & 63;
        ushort4 o;
        o.x = f2bf(acc[m][n][0] + bv); o.y = f2bf(acc[m][n][1] + bv);
        o.z = f2bf(acc[m][n][2] + bv); o.w = f2bf(acc[m][n][3] + bv);
        *(ushort4*)((ushort_t*)Cout + (((size_t)(b*16 + h))*64 + d)*1024 + t) = o;
      } else {
#pragma unroll
        for (int r = 0; r < 4; ++r){
          const int rowg = rowg0 + r;
          float val = acc[m][n][r] + bv;
          int b = rowg >> 10, t = rowg & 1023, h = colg >> 6, d = colg & 63;
          ((ushort_t*)Cout)[(((size_t)(b*16 + h))*1024 + t)*64 + d] = f2bf(val);
        }
      }
    }
  }
}

// batched Q/K/V projections straight from fp32 inputs
__global__ __launch_bounds__(256) void gemm_qkv(const float* q, const float* k,
    const float* v, const ushort_t* wqb, const ushort_t* wkb, const ushort_t* wvb,
    const float* bq, const float* bk, const float* bv,
    ushort_t* Qm, ushort_t* Km, ushort_t* Vtm)
{
  __shared__ char smem[32768];
  int id = blockIdx.x >> 8, bx = blockIdx.x & 255;
  const float* A = id==0 ? q : id==1 ? k : v;
  const ushort_t* B = id==0 ? wqb : id==1 ? wkb : wvb;
  const float* bias = id==0 ? bq : id==1 ? bk : bv;
  void* C = id==0 ? (void*)Qm : id==1 ? (void*)Km : (void*)Vtm;
  gemm_f32_body(A, B, bias, C, bx, id==2 ? 1 : 0, smem);
}

// ---------------- pipelined bf16 GEMM body (R10-verified, used by fused tail) ----------
static __device__ __forceinline__ void gemm_body(const ushort_t* __restrict__ A,
    const ushort_t* __restrict__ B, const float* __restrict__ bias,
    void* __restrict__ Cout, int bx, char* smem)
{
  constexpr int K = 1024;
  const int tid = threadIdx.x, lane = tid & 63, wv = tid >> 6;
  const int fr = lane & 15, fq = lane >> 4;
  const int wr = wv >> 1, wc = wv & 1;
  const int brow0 = ((bx & 7) * 4 + ((bx >> 3) & 3)) * 128;
  const int bcol0 = (bx >> 5) * 128;

  const f32x4 zero = {0.f, 0.f, 0.f, 0.f};
  f32x4 acc[4][4];
#pragma unroll
  for (int m = 0; m < 4; ++m)
#pragma unroll
    for (int n = 0; n < 4; ++n) acc[m][n] = zero;

  const ushort_t* Abase = A + (size_t)brow0*K;
  const ushort_t* Bbase = B + (size_t)bcol0*K;

  stage32(Abase,      K, (ushort_t*)(smem),             tid);
  stage32(Bbase,      K, (ushort_t*)(smem + 24576),     tid);
  stage32(Abase + 32, K, (ushort_t*)(smem + 8192),      tid);
  stage32(Bbase + 32, K, (ushort_t*)(smem + 24576 + 8192), tid);
  asm volatile("s_waitcnt vmcnt(4)" ::: "memory");
  __builtin_amdgcn_s_barrier();

  int rd = 0, wrb = 2;
  for (int kt = 0; kt < 32; ++kt){
    if (kt < 30){
      stage32(Abase + (kt+2)*32, K, (ushort_t*)(smem + wrb*8192),         tid);
      stage32(Bbase + (kt+2)*32, K, (ushort_t*)(smem + 24576 + wrb*8192), tid);
    }
    const ushort_t* Ac = (const ushort_t*)(smem + rd*8192);
    const ushort_t* Bc = (const ushort_t*)(smem + 24576 + rd*8192);
    bf16x8 af[4], bfg[4];
#pragma unroll
    for (int m = 0; m < 4; ++m) af[m]  = frag32(Ac, wr*64 + m*16 + fr, fq);
#pragma unroll
    for (int n = 0; n < 4; ++n) bfg[n] = frag32(Bc, wc*64 + n*16 + fr, fq);
    __builtin_amdgcn_s_setprio(1);
#pragma unroll
    for (int m = 0; m < 4; ++m)
#pragma unroll
      for (int n = 0; n < 4; ++n)
        acc[m][n] = mfma16(af[m], bfg[n], acc[m][n]);
    __builtin_amdgcn_s_setprio(0);
    __builtin_amdgcn_sched_barrier(0);
    if (kt < 30) asm volatile("s_waitcnt vmcnt(4)" ::: "memory");
    else         asm volatile("s_waitcnt vmcnt(0)" ::: "memory");
    __builtin_amdgcn_s_barrier();
    rd  = (rd  == 2) ? 0 : rd  + 1;
    wrb = (wrb == 2) ? 0 : wrb + 1;
  }

#pragma unroll
  for (int n = 0; n < 4; ++n){
    const int colg = bcol0 + wc*64 + n*16 + fr;
    const float bv = bias[colg];
#pragma unroll
    for (int m = 0; m < 4; ++m){
      const int rowg0 = brow0 + wr*64 + m*16 + fq*4;
#pragma unroll
      for (int r = 0; r < 4; ++r){
        const int rowg = rowg0 + r;
        ((float*)Cout)[(size_t)rowg*1024 + colg] = acc[m][n][r] + bv;
      }
    }
  }
}

// ---------------- attention mean over heads (recompute, m=0, Lrow only) ----------------
static __device__ __forceinline__ void attmean_body(const ushort_t* __restrict__ Q,
    const ushort_t* __restrict__ Kmat, const float* __restrict__ Lrow,
    float* __restrict__ attOut, int nb, char* smem)
{
  ushort_t* Qs0 = (ushort_t*)smem;
  ushort_t* Qs1 = (ushort_t*)(smem + 8192);
  ushort_t* Ks0 = (ushort_t*)(smem + 16384);
  ushort_t* Ks1 = (ushort_t*)(smem + 32768);
  const int tid = threadIdx.x, lane = tid & 63, wv = tid >> 6;
  const int fr = lane & 15, fq = lane >> 4;
  const int c_ = nb & 7, k_ = nb >> 3;
  const int b = c_ >> 1;
  const int rem = (c_ & 1)*64 + k_;
  const int t0 = (rem >> 3) * 64, s0 = (rem & 7) * 128;

  const f32x4 zero = {0.f, 0.f, 0.f, 0.f};
  f32x4 acc[2][4];
#pragma unroll
  for (int c = 0; c < 2; ++c)
#pragma unroll
    for (int n = 0; n < 4; ++n) acc[c][n] = zero;

  stage64<64>(Q + ((size_t)(b*16)*1024 + t0)*64, 64, Qs0, tid);
  stage64<128>(Kmat + ((size_t)(b*16)*1024 + s0)*64, 64, Ks0, tid);
  __syncthreads();

  for (int h = 0; h < 16; ++h){
    const int cur = h & 1;
    ushort_t* Qc = cur ? Qs1 : Qs0;
    ushort_t* Kc = cur ? Ks1 : Ks0;
    ushort_t* Qn = cur ? Qs0 : Qs1;
    ushort_t* Kn = cur ? Ks0 : Ks1;
    if (h < 15){
      stage64<64>(Q + ((size_t)(b*16 + h+1)*1024 + t0)*64, 64, Qn, tid);
      stage64<128>(Kmat + ((size_t)(b*16 + h+1)*1024 + s0)*64, 64, Kn, tid);
    }
    const int bh = b*16 + h;
    bf16x8 qf0 = frag64(Qc, wv*16 + fr, fq);
    bf16x8 qf1 = frag64(Qc, wv*16 + fr, 4 + fq);
    const float il = 1.f / Lrow[bh*1024 + t0 + wv*16 + fr];
#pragma unroll
    for (int c = 0; c < 2; ++c){
      f32x4 sfr[4];
      __builtin_amdgcn_s_setprio(1);
#pragma unroll
      for (int n = 0; n < 4; ++n){
        f32x4 s0v = mfma16(frag64(Kc, c*64 + n*16 + fr, fq), qf0, zero);
        sfr[n] = mfma16(frag64(Kc, c*64 + n*16 + fr, 4 + fq), qf1, s0v);
      }
      __builtin_amdgcn_s_setprio(0);
#pragma unroll
      for (int n = 0; n < 4; ++n)
#pragma unroll
        for (int r = 0; r < 4; ++r)
          acc[c][n][r] += EXP2(sfr[n][r] * QK_SCALE) * il;
    }
    __syncthreads();
  }

  const float s16 = 1.f/16.f;
#pragma unroll
  for (int c = 0; c < 2; ++c)
#pragma unroll
    for (int n = 0; n < 4; ++n){
      f32x4 v = acc[c][n];
      v[0] *= s16; v[1] *= s16; v[2] *= s16; v[3] *= s16;
      size_t idx = ((size_t)b << 20) + (size_t)(t0 + wv*16 + fr)*1024 + s0 + c*64 + n*16 + fq*4;
      *(f32x4*)(attOut + idx) = v;
    }
}

// ---------------- fused tail: gemm_o (blocks 0..255) + attmean (256..767) ----------------
__global__ __launch_bounds__(256) void fused_tail(const ushort_t* __restrict__ Yws,
    const ushort_t* __restrict__ Wob, const float* __restrict__ bo, float* __restrict__ y_out,
    const ushort_t* __restrict__ Qm, const ushort_t* __restrict__ Km,
    const float* __restrict__ Lrow, float* __restrict__ att_out)
{
  __shared__ char smem[49152];
  const int bx = blockIdx.x;
  if (bx < 256) gemm_body(Yws, Wob, bo, y_out, bx, smem);
  else          attmean_body(Qm, Km, Lrow, att_out, bx - 256, smem);
}

// ---------------- flash attention (R6-verified) + Wo-cast rider blocks ----------------
// Blocks 0..511: flash. Blocks 512..575: cast Wo fp32 -> bf16 (consumed by
// fused_tail, which launches after this kernel -> dependency satisfied).
__global__ __launch_bounds__(256, 2) void flash_kernel(const ushort_t* __restrict__ Q,
                                                       const ushort_t* __restrict__ Kmat,
                                                       const ushort_t* __restrict__ Vt,
                                                       ushort_t* __restrict__ Yws,
                                                       float* __restrict__ Lrow,
                                                       const float* __restrict__ wo,
                                                       ushort_t* __restrict__ wob)
{
  if (blockIdx.x >= 512){
    int base = (blockIdx.x - 512)*256 + threadIdx.x;   // 16384 threads
#pragma unroll
    for (int it = 0; it < 16; ++it){
      int i = base + it*16384;                          // 262144 float4 total
      float4 x = ((const float4*)wo)[i];
      ushort4 o;
      o.x = f2bf(x.x); o.y = f2bf(x.y); o.z = f2bf(x.z); o.w = f2bf(x.w);
      ((ushort4*)wob)[i] = o;
    }
    return;
  }
  __shared__ ushort_t Ks[2][64][64];
  __shared__ ushort_t Vts[2][64][64];
  __shared__ ushort_t Ps[4][32][64];   // per-wave P tile; doubles as Q staging (128 rows)
  const int tid = threadIdx.x, lane = tid & 63, wv = tid >> 6;
  const int fr = lane & 15, fq = lane >> 4;
  const int nb = blockIdx.x;
  const int bh = (nb & 7)*8 + (nb >> 6);
  const int t0 = ((nb >> 3) & 7) * 128;

  stage64<128>(Q + ((size_t)bh*1024 + t0)*64, 64, &Ps[0][0][0], tid);
  stage64<64>(Kmat + (size_t)bh*1024*64, 64, &Ks[0][0][0], tid);
  stage64<64>(Vt + (size_t)bh*64*1024, 1024, &Vts[0][0][0], tid);
  __syncthreads();
  bf16x8 aQ[2][2];
#pragma unroll
  for (int mt = 0; mt < 2; ++mt)
#pragma unroll
    for (int h = 0; h < 2; ++h)
      aQ[mt][h] = frag64(&Ps[0][0][0], wv*32 + mt*16 + fr, h*4 + fq);
  __syncthreads();

  bf16x8 ones;
#pragma unroll
  for (int i = 0; i < 8; ++i) ones[i] = (__bf16)1.0f;

  const f32x4 zero = {0.f, 0.f, 0.f, 0.f};
  f32x4 o_acc[2][4], l_acc[2];
#pragma unroll
  for (int mt = 0; mt < 2; ++mt){
    l_acc[mt] = zero;
#pragma unroll
    for (int n = 0; n < 4; ++n) o_acc[mt][n] = zero;
  }
  char* myP = (char*)&Ps[wv][0][0];

  for (int sc = 0; sc < 16; ++sc){
    const int cur = sc & 1;
    if (sc < 15){
      stage64<64>(Kmat + ((size_t)bh*1024 + (sc+1)*64)*64, 64, &Ks[cur^1][0][0], tid);
      stage64<64>(Vt + (size_t)bh*64*1024 + (sc+1)*64, 1024, &Vts[cur^1][0][0], tid);
    }
    bf16x8 kf[4][2];
#pragma unroll
    for (int n = 0; n < 4; ++n){
      kf[n][0] = frag64(&Ks[cur][0][0], n*16 + fr, fq);
      kf[n][1] = frag64(&Ks[cur][0][0], n*16 + fr, 4 + fq);
    }
    f32x4 sfr[2][4];
    __builtin_amdgcn_s_setprio(1);
#pragma unroll
    for (int mt = 0; mt < 2; ++mt)
#pragma unroll
      for (int n = 0; n < 4; ++n){
        f32x4 s0 = mfma16(kf[n][0], aQ[mt][0], zero);
        sfr[mt][n] = mfma16(kf[n][1], aQ[mt][1], s0);
      }
    __builtin_amdgcn_s_setprio(0);
#pragma unroll
    for (int mt = 0; mt < 2; ++mt){
#pragma unroll
      for (int n = 0; n < 4; ++n){
        float p0 = EXP2(sfr[mt][n][0] * QK_SCALE);
        float p1 = EXP2(sfr[mt][n][1] * QK_SCALE);
        float p2 = EXP2(sfr[mt][n][2] * QK_SCALE);
        float p3 = EXP2(sfr[mt][n][3] * QK_SCALE);
        uint2 w;
        w.x = (unsigned)f2bf(p0) | ((unsigned)f2bf(p1) << 16);
        w.y = (unsigned)f2bf(p2) | ((unsigned)f2bf(p3) << 16);
        *(uint2*)(myP + mt*2048 + fr*128 + (((n*4 + fq) ^ (fr & 14)) << 3)) = w;
      }
    }
    // FENCE: P ds_writes must complete & stay ordered before P ds_reads (same wave)
    asm volatile("s_waitcnt lgkmcnt(0)" ::: "memory");
    __builtin_amdgcn_sched_barrier(0);
    __builtin_amdgcn_s_setprio(1);
#pragma unroll
    for (int ks = 0; ks < 2; ++ks){
      bf16x8 pa[2];
#pragma unroll
      for (int mt = 0; mt < 2; ++mt){
        uint4 u = *(const uint4*)(myP + mt*2048 + fr*128 + (((ks*8 + fq*2) ^ (fr & 14)) << 3));
        pa[mt] = __builtin_bit_cast(bf16x8, u);
      }
#pragma unroll
      for (int n = 0; n < 4; ++n){
        bf16x8 vf = frag64(&Vts[cur][0][0], n*16 + fr, ks*4 + fq);
#pragma unroll
        for (int mt = 0; mt < 2; ++mt)
          o_acc[mt][n] = mfma16(pa[mt], vf, o_acc[mt][n]);
      }
#pragma unroll
      for (int mt = 0; mt < 2; ++mt)
        l_acc[mt] = mfma16(pa[mt], ones, l_acc[mt]);
    }
    __builtin_amdgcn_s_setprio(0);
    __syncthreads();
  }

  const int b = bh >> 4, h = bh & 15;
#pragma unroll
  for (int mt = 0; mt < 2; ++mt){
    float inv[4];
#pragma unroll
    for (int r = 0; r < 4; ++r) inv[r] = 1.f / l_acc[mt][r];
#pragma unroll
    for (int n = 0; n < 4; ++n)
#pragma unroll
      for (int r = 0; r < 4; ++r){
        size_t row = (size_t)b*1024 + t0 + wv*32 + mt*16 + fq*4 + r;
        Yws[row*1024 + h*64 + n*16 + fr] = f2bf(o_acc[mt][n][r] * inv[r]);
      }
  }
  if (fr == 0){
#pragma unroll
    for (int mt = 0; mt < 2; ++mt)
#pragma unroll
      for (int r = 0; r < 4; ++r)
        Lrow[bh*1024 + t0 + wv*32 + mt*16 + fq*4 + r] = l_acc[mt][r];
  }
}

// ---------------- launch ----------------
extern "C" void kernel_launch(void* const* d_in, const int* in_sizes, int n_in,
                              void* d_out, int out_size, void* d_ws, size_t ws_size,
                              hipStream_t stream)
{
  const float* q_in = (const float*)d_in[0];
  const float* k_in = (const float*)d_in[1];
  const float* v_in = (const float*)d_in[2];
  const float* Wq   = (const float*)d_in[3];
  const float* bq   = (const float*)d_in[4];
  const float* Wk   = (const float*)d_in[5];
  const float* bk   = (const float*)d_in[6];
  const float* Wv   = (const float*)d_in[7];
  const float* bv   = (const float*)d_in[8];
  const float* Wo   = (const float*)d_in[9];
  const float* bo   = (const float*)d_in[10];

  float* y_out   = (float*)d_out;
  float* att_out = y_out + (size_t)4*1024*1024;

  char* ws = (char*)d_ws;
  const size_t MB = 1024*1024;
  ushort_t* wqb  = (ushort_t*)(ws + 24*MB);
  ushort_t* wkb  = (ushort_t*)(ws + 26*MB);
  ushort_t* wvb  = (ushort_t*)(ws + 28*MB);
  ushort_t* wob  = (ushort_t*)(ws + 30*MB);
  ushort_t* Qm   = (ushort_t*)(ws + 32*MB);
  ushort_t* Km   = (ushort_t*)(ws + 40*MB);
  ushort_t* Vtm  = (ushort_t*)(ws + 48*MB);
  ushort_t* Yws  = (ushort_t*)(ws + 56*MB);
  float*    Lrow = (float*)(ws + 64*MB);

  cast_w<<<3072, 256, 0, stream>>>(Wq, Wk, Wv, ws);

  gemm_qkv<<<768, 256, 0, stream>>>(q_in, k_in, v_in, wqb, wkb, wvb,
                                    bq, bk, bv, Qm, Km, Vtm);

  flash_kernel<<<576, 256, 0, stream>>>(Qm, Km, Vtm, Yws, Lrow, Wo, wob);

  fused_tail<<<768, 256, 0, stream>>>(Yws, wob, bo, y_out, Qm, Km, Lrow, att_out);
}

// Round 19
// 119.562 us; speedup vs baseline: 1.1039x; 1.0059x over previous
//
#include <hip/hip_runtime.h>

typedef unsigned short ushort_t;
typedef __attribute__((ext_vector_type(8))) __bf16 bf16x8;
typedef __attribute__((ext_vector_type(4))) float f32x4;

#define GLD(src, lds) __builtin_amdgcn_global_load_lds( \
    (const __attribute__((address_space(1))) void*)(src), \
    (__attribute__((address_space(3))) void*)(lds), 16, 0, 0)

#if __has_builtin(__builtin_amdgcn_exp2f)
#define EXP2(x) __builtin_amdgcn_exp2f(x)
#else
#define EXP2(x) __expf((x) * 0.69314718f)
#endif
#define QK_SCALE 0.18033688f   /* 0.125 * log2(e) */

static __device__ __forceinline__ f32x4 mfma16(bf16x8 a, bf16x8 b, f32x4 c){
  return __builtin_amdgcn_mfma_f32_16x16x32_bf16(a, b, c, 0, 0, 0);
}
static __device__ __forceinline__ ushort_t f2bf(float f){
  unsigned u = __float_as_uint(f);
  return (ushort_t)((u + 0x7FFFu + ((u >> 16) & 1u)) >> 16);
}

// ---- swizzled staging / fragment reads, [R][64] bf16 tiles (flash/attmean) ----
template<int ROWS>
static __device__ __forceinline__ void stage64(const ushort_t* __restrict__ g, size_t rstride,
                                               ushort_t* lds, int tid){
#pragma unroll
  for (int r = 0; r < ROWS/32; ++r){
    int li = r*256 + tid;
    int row = li >> 3, ch = li & 7;
    GLD(g + (size_t)row*rstride + ((ch ^ (row & 7)) << 3),
        (char*)lds + (r*256 + (tid >> 6)*64)*16);
  }
}
static __device__ __forceinline__ bf16x8 frag64(const ushort_t* lds, int row, int ch){
  return *(const bf16x8*)((const char*)lds + row*128 + ((ch ^ (row & 7)) << 4));
}

// ---- [128][32] bf16 GEMM tiles (64B rows, 4 chunks of 16B), chunk ^= (row>>1)&3 ----
static __device__ __forceinline__ void stage32(const ushort_t* __restrict__ g, size_t rstride,
                                               ushort_t* lds, int tid){
#pragma unroll
  for (int r = 0; r < 2; ++r){
    int li = r*256 + tid;
    int row = li >> 2, ch = li & 3;
    GLD(g + (size_t)row*rstride + ((ch ^ ((row >> 1) & 3)) << 3),
        (char*)lds + (r*256 + (tid >> 6)*64)*16);
  }
}
static __device__ __forceinline__ bf16x8 frag32(const ushort_t* lds, int row, int ch){
  return *(const bf16x8*)((const char*)lds + row*64 + ((ch ^ ((row >> 1) & 3)) << 4));
}

// ---- A reg-staging: fp32 global -> regs (issue-early) -> RNE cvt -> bf16 LDS ----
// Thread li loads the fp32 source chunk that stage32 would place at its linear
// LDS slot (same XOR (row>>1)&3 involution); after cvt the bf16 tile in LDS is
// byte-identical to a stage32-staged tile -> frag32 reads it conflict-free.
static __device__ __forceinline__ void loadA_f32(const float* __restrict__ g,
                                                 float4 (&d)[2][2], int tid){
#pragma unroll
  for (int r = 0; r < 2; ++r){
    int li = r*256 + tid;
    int row = li >> 2;
    int lc = (li & 3) ^ ((row >> 1) & 3);
    const float* s = g + (size_t)row*1024 + lc*8;
    d[r][0] = ((const float4*)s)[0];
    d[r][1] = ((const float4*)s)[1];
  }
}
static __device__ __forceinline__ void commitA(const float4 (&d)[2][2],
                                               ushort_t* lds, int tid){
#pragma unroll
  for (int r = 0; r < 2; ++r){
    int li = r*256 + tid;
    bf16x8 o;
    o[0] = (__bf16)d[r][0].x; o[1] = (__bf16)d[r][0].y;
    o[2] = (__bf16)d[r][0].z; o[3] = (__bf16)d[r][0].w;
    o[4] = (__bf16)d[r][1].x; o[5] = (__bf16)d[r][1].y;
    o[6] = (__bf16)d[r][1].z; o[7] = (__bf16)d[r][1].w;
    *(bf16x8*)((char*)lds + li*16) = o;
  }
}

// ---------------- weight cast fp32 -> bf16 (all 4 weights, 4096 blocks) ----------------
__global__ __launch_bounds__(256) void cast_w(const float* __restrict__ wq,
    const float* __restrict__ wk, const float* __restrict__ wv,
    const float* __restrict__ wo, char* __restrict__ ws)
{
  const size_t MB = 1024*1024;
  int i = blockIdx.x*256 + threadIdx.x;   // 1048576 float4 groups
  int w = i >> 18, j = i & 262143;
  const float* src = w==0 ? wq : w==1 ? wk : w==2 ? wv : wo;
  ushort_t* dst = (ushort_t*)(ws + (24 + 2*(size_t)w)*MB);
  float4 x = ((const float4*)src)[j];
  ushort4 o;
  o.x = f2bf(x.x); o.y = f2bf(x.y); o.z = f2bf(x.z); o.w = f2bf(x.w);
  ((ushort4*)dst)[j] = o;
}

// ---------------- QKV GEMM (R15-verified): C = A_f32[M,K] * B_bf16[N,K]^T + bias ----
// 128x128 tile, BK=32, 2-phase dbuf, one barrier/K-step, 32KB LDS. A fp32
// reg-staged with early cvt; B bf16 via global_load_lds. T14 split: loads for
// kt+1 issue at loop top, cvt+ds_write after MFMA. __syncthreads (vmcnt0 drain)
// per K-step — counted-vmcnt deep pipelining is NOT sound here (R18 lesson:
// ordinary loads vs GLD intrinsics have no guaranteed emission order, so
// hand-counted vmcnt bookkeeping breaks). XCD stripe: xcd=bx&7 owns a 512-row
// A-stripe. mode 0: bf16 -> [b,h,t,d]; mode 1: bf16 -> [b,h,d,t].
static __device__ __forceinline__ void gemm_f32_body(const float* __restrict__ A,
    const ushort_t* __restrict__ B, const float* __restrict__ bias,
    void* __restrict__ Cout, int bx, int mode, char* smem)
{
  constexpr int K = 1024;
  ushort_t* As0 = (ushort_t*)smem;                    // 8KB bf16
  ushort_t* As1 = (ushort_t*)(smem + 8192);           // 8KB
  ushort_t* Bs0 = (ushort_t*)(smem + 16384);          // 8KB
  ushort_t* Bs1 = (ushort_t*)(smem + 24576);          // 8KB -> 32KB total
  const int tid = threadIdx.x, lane = tid & 63, wv = tid >> 6;
  const int fr = lane & 15, fq = lane >> 4;
  const int wr = wv >> 1, wc = wv & 1;
  const int brow0 = ((bx & 7) * 4 + ((bx >> 3) & 3)) * 128;
  const int bcol0 = (bx >> 5) * 128;

  const f32x4 zero = {0.f, 0.f, 0.f, 0.f};
  f32x4 acc[4][4];
#pragma unroll
  for (int m = 0; m < 4; ++m)
#pragma unroll
    for (int n = 0; n < 4; ++n) acc[m][n] = zero;

  float4 pfA[2][2];
  loadA_f32(A + (size_t)brow0*K, pfA, tid);
  commitA(pfA, As0, tid);
  stage32(B + (size_t)bcol0*K, K, Bs0, tid);
  __syncthreads();

  for (int kt = 0; kt < K/32; ++kt){
    const int cur = kt & 1;
    ushort_t* Ac = cur ? As1 : As0;
    ushort_t* Bc = cur ? Bs1 : Bs0;
    ushort_t* An = cur ? As0 : As1;
    ushort_t* Bn = cur ? Bs0 : Bs1;
    if (kt < K/32 - 1){
      loadA_f32(A + (size_t)brow0*K + (kt+1)*32, pfA, tid);   // issue early
      stage32(B + (size_t)bcol0*K + (kt+1)*32, K, Bn, tid);
    }
    bf16x8 af[4], bfg[4];
#pragma unroll
    for (int m = 0; m < 4; ++m) af[m]  = frag32(Ac, wr*64 + m*16 + fr, fq);
#pragma unroll
    for (int n = 0; n < 4; ++n) bfg[n] = frag32(Bc, wc*64 + n*16 + fr, fq);
    __builtin_amdgcn_s_setprio(1);
#pragma unroll
    for (int m = 0; m < 4; ++m)
#pragma unroll
      for (int n = 0; n < 4; ++n)
        acc[m][n] = mfma16(af[m], bfg[n], acc[m][n]);
    __builtin_amdgcn_s_setprio(0);
    if (kt < K/32 - 1)
      commitA(pfA, An, tid);    // cvt + ds_write after MFMA (loads have landed)
    __syncthreads();            // drains B GLDs + A ds_writes
  }

#pragma unroll
  for (int n = 0; n < 4; ++n){
    const int colg = bcol0 + wc*64 + n*16 + fr;
    const float bv = bias[colg];
#pragma unroll
    for (int m = 0; m < 4; ++m){
      const int rowg0 = brow0 + wr*64 + m*16 + fq*4;
      if (mode == 1){
        // V^T [b,h,d,t]: 4 consecutive t -> one 8B store
        int b = rowg0 >> 10, t = rowg0 & 1023, h = colg >> 6, d = colg & 63;
        ushort4 o;
        o.x = f2bf(acc[m][n][0] + bv); o.y = f2bf(acc[m][n][1] + bv);
        o.z = f2bf(acc[m][n][2] + bv); o.w = f2bf(acc[m][n][3] + bv);
        *(ushort4*)((ushort_t*)Cout + (((size_t)(b*16 + h))*64 + d)*1024 + t) = o;
      } else {
#pragma unroll
        for (int r = 0; r < 4; ++r){
          const int rowg = rowg0 + r;
          float val = acc[m][n][r] + bv;
          int b = rowg >> 10, t = rowg & 1023, h = colg >> 6, d = colg & 63;
          ((ushort_t*)Cout)[(((size_t)(b*16 + h))*1024 + t)*64 + d] = f2bf(val);
        }
      }
    }
  }
}

// batched Q/K/V projections straight from fp32 inputs
__global__ __launch_bounds__(256) void gemm_qkv(const float* q, const float* k,
    const float* v, const ushort_t* wqb, const ushort_t* wkb, const ushort_t* wvb,
    const float* bq, const float* bk, const float* bv,
    ushort_t* Qm, ushort_t* Km, ushort_t* Vtm)
{
  __shared__ char smem[32768];
  int id = blockIdx.x >> 8, bx = blockIdx.x & 255;
  const float* A = id==0 ? q : id==1 ? k : v;
  const ushort_t* B = id==0 ? wqb : id==1 ? wkb : wvb;
  const float* bias = id==0 ? bq : id==1 ? bk : bv;
  void* C = id==0 ? (void*)Qm : id==1 ? (void*)Km : (void*)Vtm;
  gemm_f32_body(A, B, bias, C, bx, id==2 ? 1 : 0, smem);
}

// ---------------- pipelined bf16 GEMM body (R10-verified, used by fused tail) ----------
// All-GLD loop: counted vmcnt is sound here (intrinsic emission order preserved).
static __device__ __forceinline__ void gemm_body(const ushort_t* __restrict__ A,
    const ushort_t* __restrict__ B, const float* __restrict__ bias,
    void* __restrict__ Cout, int bx, char* smem)
{
  constexpr int K = 1024;
  const int tid = threadIdx.x, lane = tid & 63, wv = tid >> 6;
  const int fr = lane & 15, fq = lane >> 4;
  const int wr = wv >> 1, wc = wv & 1;
  const int brow0 = ((bx & 7) * 4 + ((bx >> 3) & 3)) * 128;
  const int bcol0 = (bx >> 5) * 128;

  const f32x4 zero = {0.f, 0.f, 0.f, 0.f};
  f32x4 acc[4][4];
#pragma unroll
  for (int m = 0; m < 4; ++m)
#pragma unroll
    for (int n = 0; n < 4; ++n) acc[m][n] = zero;

  const ushort_t* Abase = A + (size_t)brow0*K;
  const ushort_t* Bbase = B + (size_t)bcol0*K;

  stage32(Abase,      K, (ushort_t*)(smem),             tid);
  stage32(Bbase,      K, (ushort_t*)(smem + 24576),     tid);
  stage32(Abase + 32, K, (ushort_t*)(smem + 8192),      tid);
  stage32(Bbase + 32, K, (ushort_t*)(smem + 24576 + 8192), tid);
  asm volatile("s_waitcnt vmcnt(4)" ::: "memory");
  __builtin_amdgcn_s_barrier();

  int rd = 0, wrb = 2;
  for (int kt = 0; kt < 32; ++kt){
    if (kt < 30){
      stage32(Abase + (kt+2)*32, K, (ushort_t*)(smem + wrb*8192),         tid);
      stage32(Bbase + (kt+2)*32, K, (ushort_t*)(smem + 24576 + wrb*8192), tid);
    }
    const ushort_t* Ac = (const ushort_t*)(smem + rd*8192);
    const ushort_t* Bc = (const ushort_t*)(smem + 24576 + rd*8192);
    bf16x8 af[4], bfg[4];
#pragma unroll
    for (int m = 0; m < 4; ++m) af[m]  = frag32(Ac, wr*64 + m*16 + fr, fq);
#pragma unroll
    for (int n = 0; n < 4; ++n) bfg[n] = frag32(Bc, wc*64 + n*16 + fr, fq);
    __builtin_amdgcn_s_setprio(1);
#pragma unroll
    for (int m = 0; m < 4; ++m)
#pragma unroll
      for (int n = 0; n < 4; ++n)
        acc[m][n] = mfma16(af[m], bfg[n], acc[m][n]);
    __builtin_amdgcn_s_setprio(0);
    __builtin_amdgcn_sched_barrier(0);
    if (kt < 30) asm volatile("s_waitcnt vmcnt(4)" ::: "memory");
    else         asm volatile("s_waitcnt vmcnt(0)" ::: "memory");
    __builtin_amdgcn_s_barrier();
    rd  = (rd  == 2) ? 0 : rd  + 1;
    wrb = (wrb == 2) ? 0 : wrb + 1;
  }

#pragma unroll
  for (int n = 0; n < 4; ++n){
    const int colg = bcol0 + wc*64 + n*16 + fr;
    const float bv = bias[colg];
#pragma unroll
    for (int m = 0; m < 4; ++m){
      const int rowg0 = brow0 + wr*64 + m*16 + fq*4;
#pragma unroll
      for (int r = 0; r < 4; ++r){
        const int rowg = rowg0 + r;
        ((float*)Cout)[(size_t)rowg*1024 + colg] = acc[m][n][r] + bv;
      }
    }
  }
}

// ---------------- attention mean over heads (recompute, m=0, Lrow only) ----------------
static __device__ __forceinline__ void attmean_body(const ushort_t* __restrict__ Q,
    const ushort_t* __restrict__ Kmat, const float* __restrict__ Lrow,
    float* __restrict__ attOut, int nb, char* smem)
{
  ushort_t* Qs0 = (ushort_t*)smem;
  ushort_t* Qs1 = (ushort_t*)(smem + 8192);
  ushort_t* Ks0 = (ushort_t*)(smem + 16384);
  ushort_t* Ks1 = (ushort_t*)(smem + 32768);
  const int tid = threadIdx.x, lane = tid & 63, wv = tid >> 6;
  const int fr = lane & 15, fq = lane >> 4;
  const int c_ = nb & 7, k_ = nb >> 3;
  const int b = c_ >> 1;
  const int rem = (c_ & 1)*64 + k_;
  const int t0 = (rem >> 3) * 64, s0 = (rem & 7) * 128;

  const f32x4 zero = {0.f, 0.f, 0.f, 0.f};
  f32x4 acc[2][4];
#pragma unroll
  for (int c = 0; c < 2; ++c)
#pragma unroll
    for (int n = 0; n < 4; ++n) acc[c][n] = zero;

  stage64<64>(Q + ((size_t)(b*16)*1024 + t0)*64, 64, Qs0, tid);
  stage64<128>(Kmat + ((size_t)(b*16)*1024 + s0)*64, 64, Ks0, tid);
  __syncthreads();

  for (int h = 0; h < 16; ++h){
    const int cur = h & 1;
    ushort_t* Qc = cur ? Qs1 : Qs0;
    ushort_t* Kc = cur ? Ks1 : Ks0;
    ushort_t* Qn = cur ? Qs0 : Qs1;
    ushort_t* Kn = cur ? Ks0 : Ks1;
    if (h < 15){
      stage64<64>(Q + ((size_t)(b*16 + h+1)*1024 + t0)*64, 64, Qn, tid);
      stage64<128>(Kmat + ((size_t)(b*16 + h+1)*1024 + s0)*64, 64, Kn, tid);
    }
    const int bh = b*16 + h;
    bf16x8 qf0 = frag64(Qc, wv*16 + fr, fq);
    bf16x8 qf1 = frag64(Qc, wv*16 + fr, 4 + fq);
    const float il = 1.f / Lrow[bh*1024 + t0 + wv*16 + fr];
#pragma unroll
    for (int c = 0; c < 2; ++c){
      f32x4 sfr[4];
      __builtin_amdgcn_s_setprio(1);
#pragma unroll
      for (int n = 0; n < 4; ++n){
        f32x4 s0v = mfma16(frag64(Kc, c*64 + n*16 + fr, fq), qf0, zero);
        sfr[n] = mfma16(frag64(Kc, c*64 + n*16 + fr, 4 + fq), qf1, s0v);
      }
      __builtin_amdgcn_s_setprio(0);
#pragma unroll
      for (int n = 0; n < 4; ++n)
#pragma unroll
        for (int r = 0; r < 4; ++r)
          acc[c][n][r] += EXP2(sfr[n][r] * QK_SCALE) * il;
    }
    __syncthreads();
  }

  const float s16 = 1.f/16.f;
#pragma unroll
  for (int c = 0; c < 2; ++c)
#pragma unroll
    for (int n = 0; n < 4; ++n){
      f32x4 v = acc[c][n];
      v[0] *= s16; v[1] *= s16; v[2] *= s16; v[3] *= s16;
      size_t idx = ((size_t)b << 20) + (size_t)(t0 + wv*16 + fr)*1024 + s0 + c*64 + n*16 + fq*4;
      *(f32x4*)(attOut + idx) = v;
    }
}

// ---------------- fused tail: gemm_o (blocks 0..255) + attmean (256..767) ----------------
__global__ __launch_bounds__(256) void fused_tail(const ushort_t* __restrict__ Yws,
    const ushort_t* __restrict__ Wob, const float* __restrict__ bo, float* __restrict__ y_out,
    const ushort_t* __restrict__ Qm, const ushort_t* __restrict__ Km,
    const float* __restrict__ Lrow, float* __restrict__ att_out)
{
  __shared__ char smem[49152];
  const int bx = blockIdx.x;
  if (bx < 256) gemm_body(Yws, Wob, bo, y_out, bx, smem);
  else          attmean_body(Qm, Km, Lrow, att_out, bx - 256, smem);
}

// ---------------- flash attention (R6-verified): QBLK=128, no online softmax ----------------
__global__ __launch_bounds__(256, 2) void flash_kernel(const ushort_t* __restrict__ Q,
                                                       const ushort_t* __restrict__ Kmat,
                                                       const ushort_t* __restrict__ Vt,
                                                       ushort_t* __restrict__ Yws,
                                                       float* __restrict__ Lrow)
{
  __shared__ ushort_t Ks[2][64][64];
  __shared__ ushort_t Vts[2][64][64];
  __shared__ ushort_t Ps[4][32][64];   // per-wave P tile; doubles as Q staging (128 rows)
  const int tid = threadIdx.x, lane = tid & 63, wv = tid >> 6;
  const int fr = lane & 15, fq = lane >> 4;
  const int nb = blockIdx.x;
  const int bh = (nb & 7)*8 + (nb >> 6);
  const int t0 = ((nb >> 3) & 7) * 128;

  stage64<128>(Q + ((size_t)bh*1024 + t0)*64, 64, &Ps[0][0][0], tid);
  stage64<64>(Kmat + (size_t)bh*1024*64, 64, &Ks[0][0][0], tid);
  stage64<64>(Vt + (size_t)bh*64*1024, 1024, &Vts[0][0][0], tid);
  __syncthreads();
  bf16x8 aQ[2][2];
#pragma unroll
  for (int mt = 0; mt < 2; ++mt)
#pragma unroll
    for (int h = 0; h < 2; ++h)
      aQ[mt][h] = frag64(&Ps[0][0][0], wv*32 + mt*16 + fr, h*4 + fq);
  __syncthreads();

  bf16x8 ones;
#pragma unroll
  for (int i = 0; i < 8; ++i) ones[i] = (__bf16)1.0f;

  const f32x4 zero = {0.f, 0.f, 0.f, 0.f};
  f32x4 o_acc[2][4], l_acc[2];
#pragma unroll
  for (int mt = 0; mt < 2; ++mt){
    l_acc[mt] = zero;
#pragma unroll
    for (int n = 0; n < 4; ++n) o_acc[mt][n] = zero;
  }
  char* myP = (char*)&Ps[wv][0][0];

  for (int sc = 0; sc < 16; ++sc){
    const int cur = sc & 1;
    if (sc < 15){
      stage64<64>(Kmat + ((size_t)bh*1024 + (sc+1)*64)*64, 64, &Ks[cur^1][0][0], tid);
      stage64<64>(Vt + (size_t)bh*64*1024 + (sc+1)*64, 1024, &Vts[cur^1][0][0], tid);
    }
    bf16x8 kf[4][2];
#pragma unroll
    for (int n = 0; n < 4; ++n){
      kf[n][0] = frag64(&Ks[cur][0][0], n*16 + fr, fq);
      kf[n][1] = frag64(&Ks[cur][0][0], n*16 + fr, 4 + fq);
    }
    f32x4 sfr[2][4];
    __builtin_amdgcn_s_setprio(1);
#pragma unroll
    for (int mt = 0; mt < 2; ++mt)
#pragma unroll
      for (int n = 0; n < 4; ++n){
        f32x4 s0 = mfma16(kf[n][0], aQ[mt][0], zero);
        sfr[mt][n] = mfma16(kf[n][1], aQ[mt][1], s0);
      }
    __builtin_amdgcn_s_setprio(0);
#pragma unroll
    for (int mt = 0; mt < 2; ++mt){
#pragma unroll
      for (int n = 0; n < 4; ++n){
        float p0 = EXP2(sfr[mt][n][0] * QK_SCALE);
        float p1 = EXP2(sfr[mt][n][1] * QK_SCALE);
        float p2 = EXP2(sfr[mt][n][2] * QK_SCALE);
        float p3 = EXP2(sfr[mt][n][3] * QK_SCALE);
        uint2 w;
        w.x = (unsigned)f2bf(p0) | ((unsigned)f2bf(p1) << 16);
        w.y = (unsigned)f2bf(p2) | ((unsigned)f2bf(p3) << 16);
        *(uint2*)(myP + mt*2048 + fr*128 + (((n*4 + fq) ^ (fr & 14)) << 3)) = w;
      }
    }
    // FENCE: P ds_writes must complete & stay ordered before P ds_reads (same wave)
    asm volatile("s_waitcnt lgkmcnt(0)" ::: "memory");
    __builtin_amdgcn_sched_barrier(0);
    __builtin_amdgcn_s_setprio(1);
#pragma unroll
    for (int ks = 0; ks < 2; ++ks){
      bf16x8 pa[2];
#pragma unroll
      for (int mt = 0; mt < 2; ++mt){
        uint4 u = *(const uint4*)(myP + mt*2048 + fr*128 + (((ks*8 + fq*2) ^ (fr & 14)) << 3));
        pa[mt] = __builtin_bit_cast(bf16x8, u);
      }
#pragma unroll
      for (int n = 0; n < 4; ++n){
        bf16x8 vf = frag64(&Vts[cur][0][0], n*16 + fr, ks*4 + fq);
#pragma unroll
        for (int mt = 0; mt < 2; ++mt)
          o_acc[mt][n] = mfma16(pa[mt], vf, o_acc[mt][n]);
      }
#pragma unroll
      for (int mt = 0; mt < 2; ++mt)
        l_acc[mt] = mfma16(pa[mt], ones, l_acc[mt]);
    }
    __builtin_amdgcn_s_setprio(0);
    __syncthreads();
  }

  const int b = bh >> 4, h = bh & 15;
#pragma unroll
  for (int mt = 0; mt < 2; ++mt){
    float inv[4];
#pragma unroll
    for (int r = 0; r < 4; ++r) inv[r] = 1.f / l_acc[mt][r];
#pragma unroll
    for (int n = 0; n < 4; ++n)
#pragma unroll
      for (int r = 0; r < 4; ++r){
        size_t row = (size_t)b*1024 + t0 + wv*32 + mt*16 + fq*4 + r;
        Yws[row*1024 + h*64 + n*16 + fr] = f2bf(o_acc[mt][n][r] * inv[r]);
      }
  }
  if (fr == 0){
#pragma unroll
    for (int mt = 0; mt < 2; ++mt)
#pragma unroll
      for (int r = 0; r < 4; ++r)
        Lrow[bh*1024 + t0 + wv*32 + mt*16 + fq*4 + r] = l_acc[mt][r];
  }
}

// ---------------- launch ----------------
extern "C" void kernel_launch(void* const* d_in, const int* in_sizes, int n_in,
                              void* d_out, int out_size, void* d_ws, size_t ws_size,
                              hipStream_t stream)
{
  const float* q_in = (const float*)d_in[0];
  const float* k_in = (const float*)d_in[1];
  const float* v_in = (const float*)d_in[2];
  const float* Wq   = (const float*)d_in[3];
  const float* bq   = (const float*)d_in[4];
  const float* Wk   = (const float*)d_in[5];
  const float* bk   = (const float*)d_in[6];
  const float* Wv   = (const float*)d_in[7];
  const float* bv   = (const float*)d_in[8];
  const float* Wo   = (const float*)d_in[9];
  const float* bo   = (const float*)d_in[10];

  float* y_out   = (float*)d_out;
  float* att_out = y_out + (size_t)4*1024*1024;

  char* ws = (char*)d_ws;
  const size_t MB = 1024*1024;
  ushort_t* wqb  = (ushort_t*)(ws + 24*MB);
  ushort_t* wkb  = (ushort_t*)(ws + 26*MB);
  ushort_t* wvb  = (ushort_t*)(ws + 28*MB);
  ushort_t* wob  = (ushort_t*)(ws + 30*MB);
  ushort_t* Qm   = (ushort_t*)(ws + 32*MB);
  ushort_t* Km   = (ushort_t*)(ws + 40*MB);
  ushort_t* Vtm  = (ushort_t*)(ws + 48*MB);
  ushort_t* Yws  = (ushort_t*)(ws + 56*MB);
  float*    Lrow = (float*)(ws + 64*MB);

  cast_w<<<4096, 256, 0, stream>>>(Wq, Wk, Wv, Wo, ws);

  gemm_qkv<<<768, 256, 0, stream>>>(q_in, k_in, v_in, wqb, wkb, wvb,
                                    bq, bk, bv, Qm, Km, Vtm);

  flash_kernel<<<512, 256, 0, stream>>>(Qm, Km, Vtm, Yws, Lrow);

  fused_tail<<<768, 256, 0, stream>>>(Yws, wob, bo, y_out, Qm, Km, Lrow, att_out);
}